// Round 15
// baseline (212.250 us; speedup 1.0000x reference)
//
#include <hip/hip_runtime.h>
#include <math.h>

#define NN   4096
#define DD   512
#define TWON 8192

typedef _Float16 half_t;
typedef unsigned short u16;
using half8  = __attribute__((ext_vector_type(8))) half_t;
using short8 = __attribute__((ext_vector_type(8))) short;
using f32x4  = __attribute__((ext_vector_type(4))) float;

__device__ __forceinline__ u16 f2bf(float f) {
    unsigned u = __float_as_uint(f);
    u += 0x7fffu + ((u >> 16) & 1u);
    return (u16)(u >> 16);
}
__device__ __forceinline__ float bf2f(u16 h) {
    return __uint_as_float(((unsigned)h) << 16);
}
__device__ __forceinline__ void gl16(const void* g, void* l) {
    __builtin_amdgcn_global_load_lds(
        (const __attribute__((address_space(1))) void*)g,
        (__attribute__((address_space(3))) void*)l, 16, 0, 0);
}
__device__ __forceinline__ f32x4 mfma16h(half8 a, half8 b, f32x4 c) {
    return __builtin_amdgcn_mfma_f32_16x16x32_f16(a, b, c, 0, 0, 0);
}
__device__ __forceinline__ f32x4 mfma16b(short8 a, short8 b, f32x4 c) {
    return __builtin_amdgcn_mfma_f32_16x16x32_bf16(a, b, c, 0, 0, 0);
}

// ---------------- prep: b=[y;x] -> f16 + norms nb[8192]
__global__ __launch_bounds__(64)
void prep_k(const float* __restrict__ x, const float* __restrict__ y,
            half_t* __restrict__ bhi, float* __restrict__ nb) {
    int r = blockIdx.x;           // 0..8191
    int l = threadIdx.x;          // 64
    const float* src = (r < NN) ? (y + (size_t)r * DD) : (x + (size_t)(r - NN) * DD);
    float4 v0 = *reinterpret_cast<const float4*>(src + l * 8);
    float4 v1 = *reinterpret_cast<const float4*>(src + l * 8 + 4);
    float e[8] = {v0.x, v0.y, v0.z, v0.w, v1.x, v1.y, v1.z, v1.w};
    float s = 0.f;
    half8 h;
    #pragma unroll
    for (int q = 0; q < 8; ++q) {
        s += e[q] * e[q];
        h[q] = (half_t)e[q];
    }
    *reinterpret_cast<half8*>(bhi + (size_t)r * DD + l * 8) = h;
    #pragma unroll
    for (int off = 32; off; off >>= 1) s += __shfl_down(s, off);
    if (l == 0) nb[r] = s;
}

// ---------------- b2tr: b2t[d][k] = sign(k) * bhi[k][d] (bf16). Separate bufs.
__global__ __launch_bounds__(256)
void b2tr_k(const half_t* __restrict__ bhi, u16* __restrict__ b2t) {
    __shared__ half_t tl[32][33];
    int k0 = blockIdx.x * 32, d0 = blockIdx.y * 32;
    int tx = threadIdx.x, ty = threadIdx.y;   // (32,8)
    #pragma unroll
    for (int j = 0; j < 4; ++j)
        tl[ty + 8 * j][tx] = bhi[(size_t)(k0 + ty + 8 * j) * DD + d0 + tx];
    __syncthreads();
    float sgn = (k0 < NN) ? 1.f : -1.f;
    #pragma unroll
    for (int j = 0; j < 4; ++j) {
        float v = (float)tl[tx][ty + 8 * j] * sgn;
        b2t[(size_t)(d0 + ty + 8 * j) * TWON + k0 + tx] = f2bf(v);
    }
}

// ---------------- GEMM1: f16 MFMA + logits; shared-C epilogue (proven r12/r14);
// stores E=exp(l-C) bf16, Ct per tile, rpm/rps row partials, cpm/cps col partials.
__global__ __launch_bounds__(256)
void gemm1_k(const half_t* __restrict__ bhi,
             const float* __restrict__ nb, u16* __restrict__ Ef,
             float* __restrict__ Ct,
             float* __restrict__ rpm, float* __restrict__ rps,
             float* __restrict__ cpm, float* __restrict__ cps) {
    __shared__ unsigned char lds[32768]; // Ahi@0 Bhi@16K, each 128x64 f16 swizzled
    const int t = threadIdx.x;
    const int wave = t >> 6, lane = t & 63;
    const int i0 = blockIdx.y * 128, j0 = blockIdx.x * 128;
    const int wm = (wave >> 1) * 64, wn = (wave & 1) * 64;
    const half_t* ahig = bhi + (size_t)NN * DD;  // x rows are b rows 4096..8191
    f32x4 acc[4][4] = {};
    for (int k0 = 0; k0 < DD; k0 += 64) {
        __syncthreads();
        #pragma unroll
        for (int q = 0; q < 4; ++q) {
            const int dbase = (wave * 4 + q) * 1024;
            const int p  = dbase + lane * 16;
            const int r  = p >> 7;
            const int cb = (p & 127) ^ ((r & 7) << 4);
            const size_t offA = (size_t)(i0 + r) * DD + k0 + (cb >> 1);
            const size_t offB = (size_t)(j0 + r) * DD + k0 + (cb >> 1);
            gl16(ahig + offA, lds + dbase);
            gl16(bhi  + offB, lds + 16384 + dbase);
        }
        asm volatile("s_waitcnt vmcnt(0)" ::: "memory");
        __builtin_amdgcn_sched_barrier(0);
        __syncthreads();
        #pragma unroll
        for (int kk = 0; kk < 2; ++kk) {
            half8 ah[4];
            #pragma unroll
            for (int m = 0; m < 4; ++m) {
                const int row = wm + m * 16 + (lane & 15);
                const int off = row * 128 + ((kk * 64 + (lane >> 4) * 16) ^ ((row & 7) << 4));
                ah[m] = *reinterpret_cast<const half8*>(lds + off);
            }
            #pragma unroll
            for (int n = 0; n < 4; ++n) {
                const int row = wn + n * 16 + (lane & 15);
                const int off = row * 128 + ((kk * 64 + (lane >> 4) * 16) ^ ((row & 7) << 4));
                half8 bh = *reinterpret_cast<const half8*>(lds + 16384 + off);
                #pragma unroll
                for (int m = 0; m < 4; ++m)
                    acc[m][n] = mfma16h(ah[m], bh, acc[m][n]);
            }
        }
    }
    float nbj[4];
    #pragma unroll
    for (int n = 0; n < 4; ++n) nbj[n] = nb[j0 + wn + n * 16 + (lane & 15)];
    float tmax = -3.0e38f;
    #pragma unroll
    for (int m = 0; m < 4; ++m) {
        #pragma unroll
        for (int r4 = 0; r4 < 4; ++r4) {
            const int i = i0 + wm + m * 16 + (lane >> 4) * 4 + r4;
            const float nxi = nb[NN + i];
            #pragma unroll
            for (int n = 0; n < 4; ++n) {
                const int j = j0 + wn + n * 16 + (lane & 15);
                float sq = nxi + nbj[n] - 2.0f * acc[m][n][r4];
                float lg = -10.0f * sqrtf(fmaxf(sq, 1e-12f));
                if (j == i + NN) lg = -1e7f;
                acc[m][n][r4] = lg;
                tmax = fmaxf(tmax, lg);
            }
        }
    }
    #pragma unroll
    for (int off = 1; off < 64; off <<= 1) tmax = fmaxf(tmax, __shfl_xor(tmax, off));
    __syncthreads();
    float* red = reinterpret_cast<float*>(lds);
    if (lane == 0) red[wave] = tmax;
    __syncthreads();
    const float C = fmaxf(fmaxf(red[0], red[1]), fmaxf(red[2], red[3]));
    __syncthreads();
    if (t == 0) Ct[blockIdx.y * 64 + blockIdx.x] = C;
    float rs[16] = {}, cs[4] = {};
    #pragma unroll
    for (int m = 0; m < 4; ++m)
        #pragma unroll
        for (int r4 = 0; r4 < 4; ++r4) {
            const int idx = m * 4 + r4;
            const int i = i0 + wm + m * 16 + (lane >> 4) * 4 + r4;
            #pragma unroll
            for (int n = 0; n < 4; ++n) {
                const int j = j0 + wn + n * 16 + (lane & 15);
                float e = __expf(acc[m][n][r4] - C);
                Ef[(size_t)i * TWON + j] = f2bf(e);
                rs[idx] += e;
                cs[n]   += e;
            }
        }
    #pragma unroll
    for (int off = 1; off < 16; off <<= 1) {
        #pragma unroll
        for (int idx = 0; idx < 16; ++idx) rs[idx] += __shfl_xor(rs[idx], off);
    }
    #pragma unroll
    for (int off = 16; off < 64; off <<= 1) {
        #pragma unroll
        for (int n = 0; n < 4; ++n) cs[n] += __shfl_xor(cs[n], off);
    }
    if ((lane & 15) == 0) {
        #pragma unroll
        for (int m = 0; m < 4; ++m)
            #pragma unroll
            for (int r4 = 0; r4 < 4; ++r4) {
                const int r = wm + m * 16 + (lane >> 4) * 4 + r4;
                red[(wave & 1) * 128 + r] = rs[m * 4 + r4];
            }
    }
    if (lane < 16) {
        #pragma unroll
        for (int n = 0; n < 4; ++n) {
            const int c = wn + n * 16 + lane;
            red[256 + (wave >> 1) * 128 + c] = cs[n];
        }
    }
    __syncthreads();
    if (t < 128) {
        float S = red[t] + red[128 + t];
        rpm[(size_t)blockIdx.x * NN + i0 + t] = C;
        rps[(size_t)blockIdx.x * NN + i0 + t] = S;
    } else {
        const int c = t - 128;
        float S = red[256 + c] + red[384 + c];
        cpm[(size_t)blockIdx.y * TWON + j0 + c] = C;
        cps[(size_t)blockIdx.y * TWON + j0 + c] = S;
    }
}

// ---------------- combine row partials -> rm, rrs
__global__ __launch_bounds__(256)
void row_comb_k(const float* __restrict__ rpm, const float* __restrict__ rps,
                float* __restrict__ rm, float* __restrict__ rrs) {
    int i = blockIdx.x * 256 + threadIdx.x;
    float M = -3.0e38f;
    for (int tt = 0; tt < TWON / 128; ++tt) M = fmaxf(M, rpm[(size_t)tt * NN + i]);
    float S = 0.f;
    for (int tt = 0; tt < TWON / 128; ++tt)
        S += rps[(size_t)tt * NN + i] * __expf(rpm[(size_t)tt * NN + i] - M);
    rm[i] = M; rrs[i] = rsqrtf(S);
}

// ---------------- combine col partials -> Pj = -cm/2 + ln(rcs)
__global__ __launch_bounds__(256)
void col_comb_k(const float* __restrict__ cpm, const float* __restrict__ cps,
                float* __restrict__ Pj) {
    int j = blockIdx.x * 256 + threadIdx.x;
    float M = -3.0e38f;
    for (int tt = 0; tt < NN / 128; ++tt) M = fmaxf(M, cpm[(size_t)tt * TWON + j]);
    float S = 0.f;
    for (int tt = 0; tt < NN / 128; ++tt)
        S += cps[(size_t)tt * TWON + j] * __expf(cpm[(size_t)tt * TWON + j] - M);
    Pj[j] = -0.5f * M - 0.5f * logf(S);    // = -cm/2 + ln(rcs)
}

// ---------------- GEMM2 v3: block tile 128i x 256d x 2048k (L3-traffic-optimal
// at 256 blocks): grid = 32 iblk x 2 db x 4 kslice, 1 block/CU.
// 8 waves = 2(m-half) x 4(d-quarter); per-wave acc[4][4] (r12-proven loop).
// Fused-transform reg-staged A (2 rows/thread), dbuf LDS (2x16KB), B frags
// direct, issued FIRST each phase (counted vmcnt). Packed-bf16 partials.
__global__ __launch_bounds__(512, 2)
void gemm2_k(const u16* __restrict__ Ef, const u16* __restrict__ b2t,
             const float* __restrict__ Ct, const float* __restrict__ rm,
             const float* __restrict__ Pj, const float* __restrict__ rrs,
             unsigned* __restrict__ part) {
    __shared__ unsigned char lds[32768];   // 2 x (128x64 bf16 A tile, swizzled)
    const int t = threadIdx.x;
    const int wave = t >> 6, lane = t & 63;
    const int sw = blockIdx.x;             // 0..255
    const int kslice = sw & 3;
    const int db = (sw >> 2) & 1;
    const int iblk = sw >> 3;              // 0..31
    const int i0 = iblk * 128;
    const int d0 = db * 256;
    const int kbase = kslice * 2048;
    const int mh = wave >> 2, dq = wave & 3;
    const int sr = t >> 3;          // staging row 0..63 (and +64)
    const int kc = (t & 7) * 8;     // staging k-offset (elements)
    const int awb = sr * 128 + ((kc * 2) ^ ((sr & 7) << 4));
    const int NT = 32;
    const float rmh0 = 0.5f * rm[i0 + sr];
    const float rmh1 = 0.5f * rm[i0 + 64 + sr];
    f32x4 acc[4][4] = {};
    short8 aE0, aE1;
    float4 p0, p1;
    float arg0, arg1;
    auto LOADA = [&](int it) {
        const int k = kbase + it * 64 + kc;
        aE0 = *reinterpret_cast<const short8*>(Ef + (size_t)(i0 + sr) * TWON + k);
        aE1 = *reinterpret_cast<const short8*>(Ef + (size_t)(i0 + 64 + sr) * TWON + k);
        p0 = *reinterpret_cast<const float4*>(Pj + k);
        p1 = *reinterpret_cast<const float4*>(Pj + k + 4);
        const float ct = Ct[iblk * 64 + ((kbase + it * 64) >> 7)];
        arg0 = ct - rmh0;
        arg1 = ct - rmh1;
    };
    auto STOREA = [&](int buf) {
        short8 g;
        g[0] = (short)f2bf(bf2f((u16)aE0[0]) * __expf(arg0 + p0.x));
        g[1] = (short)f2bf(bf2f((u16)aE0[1]) * __expf(arg0 + p0.y));
        g[2] = (short)f2bf(bf2f((u16)aE0[2]) * __expf(arg0 + p0.z));
        g[3] = (short)f2bf(bf2f((u16)aE0[3]) * __expf(arg0 + p0.w));
        g[4] = (short)f2bf(bf2f((u16)aE0[4]) * __expf(arg0 + p1.x));
        g[5] = (short)f2bf(bf2f((u16)aE0[5]) * __expf(arg0 + p1.y));
        g[6] = (short)f2bf(bf2f((u16)aE0[6]) * __expf(arg0 + p1.z));
        g[7] = (short)f2bf(bf2f((u16)aE0[7]) * __expf(arg0 + p1.w));
        *reinterpret_cast<short8*>(lds + buf * 16384 + awb) = g;
        short8 h;
        h[0] = (short)f2bf(bf2f((u16)aE1[0]) * __expf(arg1 + p0.x));
        h[1] = (short)f2bf(bf2f((u16)aE1[1]) * __expf(arg1 + p0.y));
        h[2] = (short)f2bf(bf2f((u16)aE1[2]) * __expf(arg1 + p0.z));
        h[3] = (short)f2bf(bf2f((u16)aE1[3]) * __expf(arg1 + p0.w));
        h[4] = (short)f2bf(bf2f((u16)aE1[4]) * __expf(arg1 + p1.x));
        h[5] = (short)f2bf(bf2f((u16)aE1[5]) * __expf(arg1 + p1.y));
        h[6] = (short)f2bf(bf2f((u16)aE1[6]) * __expf(arg1 + p1.z));
        h[7] = (short)f2bf(bf2f((u16)aE1[7]) * __expf(arg1 + p1.w));
        *reinterpret_cast<short8*>(lds + buf * 16384 + 8192 + awb) = h;
    };
    LOADA(0);
    STOREA(0);
    __syncthreads();
    int cur = 0;
    for (int it = 0; it < NT; ++it) {
        // B fragments FIRST (oldest vmcnt entries -> counted wait, not drain)
        short8 bfr0[4], bfr1[4];
        #pragma unroll
        for (int n = 0; n < 4; ++n) {
            const int d = d0 + dq * 64 + n * 16 + (lane & 15);
            const u16* bp = b2t + (size_t)d * TWON + kbase + it * 64 + (lane >> 4) * 8;
            bfr0[n] = *reinterpret_cast<const short8*>(bp);
            bfr1[n] = *reinterpret_cast<const short8*>(bp + 32);
        }
        if (it + 1 < NT) LOADA(it + 1);    // next-A issue (consumed after MFMA)
        #pragma unroll
        for (int kk = 0; kk < 2; ++kk) {
            short8 af[4];
            #pragma unroll
            for (int m = 0; m < 4; ++m) {
                const int row = mh * 64 + m * 16 + (lane & 15);
                const int off = cur * 16384 + row * 128 +
                                ((kk * 64 + (lane >> 4) * 16) ^ ((row & 7) << 4));
                af[m] = *reinterpret_cast<const short8*>(lds + off);
            }
            #pragma unroll
            for (int m = 0; m < 4; ++m)
                #pragma unroll
                for (int n = 0; n < 4; ++n)
                    acc[m][n] = mfma16b(af[m], (kk == 0) ? bfr0[n] : bfr1[n], acc[m][n]);
        }
        if (it + 1 < NT) STOREA(cur ^ 1);  // transform + stage into other buffer
        __syncthreads();
        cur ^= 1;
    }
    // ---- epilogue: pack acc*rrs to bf16 pairs, raw lane-order coalesced store
    unsigned* pout = part + ((size_t)(kslice * 64 + iblk * 2 + db) * 512 + t) * 32;
    #pragma unroll
    for (int m = 0; m < 4; ++m) {
        float rf[4];
        #pragma unroll
        for (int r4 = 0; r4 < 4; ++r4)
            rf[r4] = rrs[i0 + mh * 64 + m * 16 + (lane >> 4) * 4 + r4];
        unsigned pk[8];
        #pragma unroll
        for (int n = 0; n < 4; ++n) {
            pk[n * 2]     = (unsigned)f2bf(acc[m][n][0] * rf[0]) |
                            ((unsigned)f2bf(acc[m][n][1] * rf[1]) << 16);
            pk[n * 2 + 1] = (unsigned)f2bf(acc[m][n][2] * rf[2]) |
                            ((unsigned)f2bf(acc[m][n][3] * rf[3]) << 16);
        }
        *reinterpret_cast<uint4*>(pout + m * 8)     = *reinterpret_cast<uint4*>(pk);
        *reinterpret_cast<uint4*>(pout + m * 8 + 4) = *reinterpret_cast<uint4*>(pk + 4);
    }
}

// ---------------- reduce: sum 4 packed-bf16 raw-order slices -> out[i][d] f32
__global__ __launch_bounds__(512)
void reduce_k(const unsigned* __restrict__ part, float* __restrict__ out) {
    const int b = blockIdx.x;            // 0..255: mq | db | iblk
    const int mq = b & 3, db = (b >> 2) & 1, iblk = b >> 3;
    const int t = threadIdx.x;
    const int lane = t & 63, wave = t >> 6;
    const int mh = wave >> 2, dq = wave & 3;
    float s[16] = {};
    #pragma unroll
    for (int ks = 0; ks < 4; ++ks) {
        const unsigned* p = part + ((size_t)(ks * 64 + iblk * 2 + db) * 512 + t) * 32 + mq * 8;
        uint4 a = *reinterpret_cast<const uint4*>(p);
        uint4 c = *reinterpret_cast<const uint4*>(p + 4);
        unsigned u[8] = {a.x, a.y, a.z, a.w, c.x, c.y, c.z, c.w};
        #pragma unroll
        for (int n = 0; n < 4; ++n) {
            s[n * 4 + 0] += bf2f((u16)(u[n * 2] & 0xffffu));
            s[n * 4 + 1] += bf2f((u16)(u[n * 2] >> 16));
            s[n * 4 + 2] += bf2f((u16)(u[n * 2 + 1] & 0xffffu));
            s[n * 4 + 3] += bf2f((u16)(u[n * 2 + 1] >> 16));
        }
    }
    #pragma unroll
    for (int n = 0; n < 4; ++n)
        #pragma unroll
        for (int r4 = 0; r4 < 4; ++r4) {
            const int i = iblk * 128 + mh * 64 + mq * 16 + (lane >> 4) * 4 + r4;
            const int d = db * 256 + dq * 64 + n * 16 + (lane & 15);
            out[(size_t)i * DD + d] = s[n * 4 + r4];
        }
}

extern "C" void kernel_launch(void* const* d_in, const int* in_sizes, int n_in,
                              void* d_out, int out_size, void* d_ws, size_t ws_size,
                              hipStream_t stream) {
    const float* x = (const float*)d_in[0];
    const float* y = (const float*)d_in[1];
    float* out = (float*)d_out;

    char* w = (char*)d_ws;
    const size_t OFF_EF   = 0;                          // Ef bf16: 64 MiB
    const size_t OFF_BHI  = 67108864;                   // bhi f16: 8 MiB
    const size_t OFF_B2T  = OFF_BHI + 8388608;          // b2t bf16: 8 MiB
    const size_t OFF_PART = OFF_B2T + 8388608;          // part packed bf16: 16 MiB
    const size_t OFF_RPM  = OFF_PART + 67108864;        // 1 MiB each
    const size_t OFF_RPS  = OFF_RPM + 1048576;
    const size_t OFF_CPM  = OFF_RPS + 1048576;
    const size_t OFF_CPS  = OFF_CPM + 1048576;
    const size_t OFF_CT   = OFF_CPS + 1048576;          // 8 KiB (+pad)
    const size_t OFF_TAIL = OFF_CT + 65536;

    u16*      Ef   = (u16*)(w + OFF_EF);
    half_t*   bhi  = (half_t*)(w + OFF_BHI);
    u16*      b2t  = (u16*)(w + OFF_B2T);
    unsigned* part = (unsigned*)(w + OFF_PART);
    float*    rpm  = (float*)(w + OFF_RPM);
    float*    rps  = (float*)(w + OFF_RPS);
    float*    cpm  = (float*)(w + OFF_CPM);
    float*    cps  = (float*)(w + OFF_CPS);
    float*    Ct   = (float*)(w + OFF_CT);
    float*    nb   = (float*)(w + OFF_TAIL);            // 8192
    float*    rm   = nb  + TWON;                        // 4096
    float*    rrs  = rm  + NN;                          // 4096
    float*    Pj   = rrs + NN;                          // 8192

    prep_k<<<TWON, 64, 0, stream>>>(x, y, bhi, nb);
    gemm1_k<<<dim3(TWON / 128, NN / 128), 256, 0, stream>>>(bhi, nb, Ef, Ct,
                                                            rpm, rps, cpm, cps);
    row_comb_k<<<NN / 256, 256, 0, stream>>>(rpm, rps, rm, rrs);
    col_comb_k<<<TWON / 256, 256, 0, stream>>>(cpm, cps, Pj);
    b2tr_k<<<dim3(TWON / 32, DD / 32), dim3(32, 8), 0, stream>>>(bhi, b2t);
    gemm2_k<<<256, 512, 0, stream>>>(Ef, b2t, Ct, rm, Pj, rrs, part);
    reduce_k<<<256, 512, 0, stream>>>(part, out);
}

// Round 16
// 187.421 us; speedup vs baseline: 1.1325x; 1.1325x over previous
//
#include <hip/hip_runtime.h>
#include <math.h>

#define NN   4096
#define DD   512
#define TWON 8192

typedef _Float16 half_t;
typedef unsigned short u16;
using half8  = __attribute__((ext_vector_type(8))) half_t;
using short8 = __attribute__((ext_vector_type(8))) short;
using f32x4  = __attribute__((ext_vector_type(4))) float;

__device__ __forceinline__ u16 f2bf(float f) {
    unsigned u = __float_as_uint(f);
    u += 0x7fffu + ((u >> 16) & 1u);
    return (u16)(u >> 16);
}
__device__ __forceinline__ float bf2f(u16 h) {
    return __uint_as_float(((unsigned)h) << 16);
}
__device__ __forceinline__ void gl16(const void* g, void* l) {
    __builtin_amdgcn_global_load_lds(
        (const __attribute__((address_space(1))) void*)g,
        (__attribute__((address_space(3))) void*)l, 16, 0, 0);
}
__device__ __forceinline__ f32x4 mfma16h(half8 a, half8 b, f32x4 c) {
    return __builtin_amdgcn_mfma_f32_16x16x32_f16(a, b, c, 0, 0, 0);
}
__device__ __forceinline__ f32x4 mfma16b(short8 a, short8 b, f32x4 c) {
    return __builtin_amdgcn_mfma_f32_16x16x32_bf16(a, b, c, 0, 0, 0);
}

// ---------------- prep: b=[y;x] -> f16 + norms nb[8192]
__global__ __launch_bounds__(64)
void prep_k(const float* __restrict__ x, const float* __restrict__ y,
            half_t* __restrict__ bhi, float* __restrict__ nb) {
    int r = blockIdx.x;           // 0..8191
    int l = threadIdx.x;          // 64
    const float* src = (r < NN) ? (y + (size_t)r * DD) : (x + (size_t)(r - NN) * DD);
    float4 v0 = *reinterpret_cast<const float4*>(src + l * 8);
    float4 v1 = *reinterpret_cast<const float4*>(src + l * 8 + 4);
    float e[8] = {v0.x, v0.y, v0.z, v0.w, v1.x, v1.y, v1.z, v1.w};
    float s = 0.f;
    half8 h;
    #pragma unroll
    for (int q = 0; q < 8; ++q) {
        s += e[q] * e[q];
        h[q] = (half_t)e[q];
    }
    *reinterpret_cast<half8*>(bhi + (size_t)r * DD + l * 8) = h;
    #pragma unroll
    for (int off = 32; off; off >>= 1) s += __shfl_down(s, off);
    if (l == 0) nb[r] = s;
}

// ---------------- b2tr: b2t[d][k] = sign(k) * bhi[k][d] (bf16). Separate bufs.
__global__ __launch_bounds__(256)
void b2tr_k(const half_t* __restrict__ bhi, u16* __restrict__ b2t) {
    __shared__ half_t tl[32][33];
    int k0 = blockIdx.x * 32, d0 = blockIdx.y * 32;
    int tx = threadIdx.x, ty = threadIdx.y;   // (32,8)
    #pragma unroll
    for (int j = 0; j < 4; ++j)
        tl[ty + 8 * j][tx] = bhi[(size_t)(k0 + ty + 8 * j) * DD + d0 + tx];
    __syncthreads();
    float sgn = (k0 < NN) ? 1.f : -1.f;
    #pragma unroll
    for (int j = 0; j < 4; ++j) {
        float v = (float)tl[tx][ty + 8 * j] * sgn;
        b2t[(size_t)(d0 + ty + 8 * j) * TWON + k0 + tx] = f2bf(v);
    }
}

// ---------------- GEMM1: f16 MFMA + logits; shared-C epilogue (proven r12/r14);
// stores E=exp(l-C) bf16, Ct per tile, rpm/rps row partials, cpm/cps col partials.
__global__ __launch_bounds__(256)
void gemm1_k(const half_t* __restrict__ bhi,
             const float* __restrict__ nb, u16* __restrict__ Ef,
             float* __restrict__ Ct,
             float* __restrict__ rpm, float* __restrict__ rps,
             float* __restrict__ cpm, float* __restrict__ cps) {
    __shared__ unsigned char lds[32768]; // Ahi@0 Bhi@16K, each 128x64 f16 swizzled
    const int t = threadIdx.x;
    const int wave = t >> 6, lane = t & 63;
    const int i0 = blockIdx.y * 128, j0 = blockIdx.x * 128;
    const int wm = (wave >> 1) * 64, wn = (wave & 1) * 64;
    const half_t* ahig = bhi + (size_t)NN * DD;  // x rows are b rows 4096..8191
    f32x4 acc[4][4] = {};
    for (int k0 = 0; k0 < DD; k0 += 64) {
        __syncthreads();
        #pragma unroll
        for (int q = 0; q < 4; ++q) {
            const int dbase = (wave * 4 + q) * 1024;
            const int p  = dbase + lane * 16;
            const int r  = p >> 7;
            const int cb = (p & 127) ^ ((r & 7) << 4);
            const size_t offA = (size_t)(i0 + r) * DD + k0 + (cb >> 1);
            const size_t offB = (size_t)(j0 + r) * DD + k0 + (cb >> 1);
            gl16(ahig + offA, lds + dbase);
            gl16(bhi  + offB, lds + 16384 + dbase);
        }
        asm volatile("s_waitcnt vmcnt(0)" ::: "memory");
        __builtin_amdgcn_sched_barrier(0);
        __syncthreads();
        #pragma unroll
        for (int kk = 0; kk < 2; ++kk) {
            half8 ah[4];
            #pragma unroll
            for (int m = 0; m < 4; ++m) {
                const int row = wm + m * 16 + (lane & 15);
                const int off = row * 128 + ((kk * 64 + (lane >> 4) * 16) ^ ((row & 7) << 4));
                ah[m] = *reinterpret_cast<const half8*>(lds + off);
            }
            #pragma unroll
            for (int n = 0; n < 4; ++n) {
                const int row = wn + n * 16 + (lane & 15);
                const int off = row * 128 + ((kk * 64 + (lane >> 4) * 16) ^ ((row & 7) << 4));
                half8 bh = *reinterpret_cast<const half8*>(lds + 16384 + off);
                #pragma unroll
                for (int m = 0; m < 4; ++m)
                    acc[m][n] = mfma16h(ah[m], bh, acc[m][n]);
            }
        }
    }
    float nbj[4];
    #pragma unroll
    for (int n = 0; n < 4; ++n) nbj[n] = nb[j0 + wn + n * 16 + (lane & 15)];
    float tmax = -3.0e38f;
    #pragma unroll
    for (int m = 0; m < 4; ++m) {
        #pragma unroll
        for (int r4 = 0; r4 < 4; ++r4) {
            const int i = i0 + wm + m * 16 + (lane >> 4) * 4 + r4;
            const float nxi = nb[NN + i];
            #pragma unroll
            for (int n = 0; n < 4; ++n) {
                const int j = j0 + wn + n * 16 + (lane & 15);
                float sq = nxi + nbj[n] - 2.0f * acc[m][n][r4];
                float lg = -10.0f * sqrtf(fmaxf(sq, 1e-12f));
                if (j == i + NN) lg = -1e7f;
                acc[m][n][r4] = lg;
                tmax = fmaxf(tmax, lg);
            }
        }
    }
    #pragma unroll
    for (int off = 1; off < 64; off <<= 1) tmax = fmaxf(tmax, __shfl_xor(tmax, off));
    __syncthreads();
    float* red = reinterpret_cast<float*>(lds);
    if (lane == 0) red[wave] = tmax;
    __syncthreads();
    const float C = fmaxf(fmaxf(red[0], red[1]), fmaxf(red[2], red[3]));
    __syncthreads();
    if (t == 0) Ct[blockIdx.y * 64 + blockIdx.x] = C;
    float rs[16] = {}, cs[4] = {};
    #pragma unroll
    for (int m = 0; m < 4; ++m)
        #pragma unroll
        for (int r4 = 0; r4 < 4; ++r4) {
            const int idx = m * 4 + r4;
            const int i = i0 + wm + m * 16 + (lane >> 4) * 4 + r4;
            #pragma unroll
            for (int n = 0; n < 4; ++n) {
                const int j = j0 + wn + n * 16 + (lane & 15);
                float e = __expf(acc[m][n][r4] - C);
                Ef[(size_t)i * TWON + j] = f2bf(e);
                rs[idx] += e;
                cs[n]   += e;
            }
        }
    #pragma unroll
    for (int off = 1; off < 16; off <<= 1) {
        #pragma unroll
        for (int idx = 0; idx < 16; ++idx) rs[idx] += __shfl_xor(rs[idx], off);
    }
    #pragma unroll
    for (int off = 16; off < 64; off <<= 1) {
        #pragma unroll
        for (int n = 0; n < 4; ++n) cs[n] += __shfl_xor(cs[n], off);
    }
    if ((lane & 15) == 0) {
        #pragma unroll
        for (int m = 0; m < 4; ++m)
            #pragma unroll
            for (int r4 = 0; r4 < 4; ++r4) {
                const int r = wm + m * 16 + (lane >> 4) * 4 + r4;
                red[(wave & 1) * 128 + r] = rs[m * 4 + r4];
            }
    }
    if (lane < 16) {
        #pragma unroll
        for (int n = 0; n < 4; ++n) {
            const int c = wn + n * 16 + lane;
            red[256 + (wave >> 1) * 128 + c] = cs[n];
        }
    }
    __syncthreads();
    if (t < 128) {
        float S = red[t] + red[128 + t];
        rpm[(size_t)blockIdx.x * NN + i0 + t] = C;
        rps[(size_t)blockIdx.x * NN + i0 + t] = S;
    } else {
        const int c = t - 128;
        float S = red[256 + c] + red[384 + c];
        cpm[(size_t)blockIdx.y * TWON + j0 + c] = C;
        cps[(size_t)blockIdx.y * TWON + j0 + c] = S;
    }
}

// ---------------- combine row partials -> rm, rrs
__global__ __launch_bounds__(256)
void row_comb_k(const float* __restrict__ rpm, const float* __restrict__ rps,
                float* __restrict__ rm, float* __restrict__ rrs) {
    int i = blockIdx.x * 256 + threadIdx.x;
    float M = -3.0e38f;
    for (int tt = 0; tt < TWON / 128; ++tt) M = fmaxf(M, rpm[(size_t)tt * NN + i]);
    float S = 0.f;
    for (int tt = 0; tt < TWON / 128; ++tt)
        S += rps[(size_t)tt * NN + i] * __expf(rpm[(size_t)tt * NN + i] - M);
    rm[i] = M; rrs[i] = rsqrtf(S);
}

// ---------------- combine col partials -> Pj = -cm/2 + ln(rcs)
__global__ __launch_bounds__(256)
void col_comb_k(const float* __restrict__ cpm, const float* __restrict__ cps,
                float* __restrict__ Pj) {
    int j = blockIdx.x * 256 + threadIdx.x;
    float M = -3.0e38f;
    for (int tt = 0; tt < NN / 128; ++tt) M = fmaxf(M, cpm[(size_t)tt * TWON + j]);
    float S = 0.f;
    for (int tt = 0; tt < NN / 128; ++tt)
        S += cps[(size_t)tt * TWON + j] * __expf(cpm[(size_t)tt * TWON + j] - M);
    Pj[j] = -0.5f * M - 0.5f * logf(S);    // = -cm/2 + ln(rcs)
}

// ---------------- GEMM2 v4: block 128i x 128d x 1024k; grid 1024 (kslice=XCD).
// BOTH operands staged in LDS: B via gl16 (async, gemm1-proven idiom), A via
// fused-exp reg path. Single-buffer phase = gemm1's proven K-loop shape:
// barrier -> stage -> vmcnt(0) -> barrier -> MFMA. 8 waves = 2m x 4d,
// acc[4][2]/wave (32 AGPR). Packed-bf16 partials.
__global__ __launch_bounds__(512, 4)
void gemm2_k(const u16* __restrict__ Ef, const u16* __restrict__ b2t,
             const float* __restrict__ Ct, const float* __restrict__ rm,
             const float* __restrict__ Pj, const float* __restrict__ rrs,
             unsigned* __restrict__ part) {
    __shared__ unsigned char lds[32768];   // A 128x64 bf16 @0, B 128x64 bf16 @16384
    const int t = threadIdx.x;
    const int wave = t >> 6, lane = t & 63;
    const int sw = blockIdx.x;             // 0..1023
    const int kslice = sw & 7;             // = XCD (round-robin dispatch)
    const int idx2 = sw >> 3;              // 0..127
    const int db = idx2 & 3;               // d-block
    const int iblk = idx2 >> 2;            // 0..31
    const int i0 = iblk * 128;
    const int d0 = db * 128;
    const int kbase = kslice * 1024;
    const int mh = wave >> 2, dq = wave & 3;
    const int sr = t >> 2;                 // A staging row 0..127
    const int kc = (t & 3) * 16;           // A staging k-offset (elements)
    const int aw0 = sr * 128 + ((kc * 2) ^ ((sr & 7) << 4));
    const int aw1 = sr * 128 + (((kc + 8) * 2) ^ ((sr & 7) << 4));
    const float rmh = 0.5f * rm[i0 + sr];
    const int NT = 16;                     // 1024 / 64
    f32x4 acc[4][2] = {};
    for (int it = 0; it < NT; ++it) {
        __syncthreads();
        // ---- B stage via gl16 (pre-swizzled source, linear LDS dest)
        #pragma unroll
        for (int q = 0; q < 2; ++q) {
            const int dbase = (wave * 2 + q) * 1024;
            const int p  = dbase + lane * 16;
            const int r  = p >> 7;                      // d-row 0..127
            const int cb = (p & 127) ^ ((r & 7) << 4);
            gl16(b2t + (size_t)(d0 + r) * TWON + kbase + it * 64 + (cb >> 1),
                 lds + 16384 + dbase);
        }
        // ---- A stage: Ef row + fused exp -> swizzled ds_write
        {
            const int k = kbase + it * 64 + kc;
            const u16* ep = Ef + (size_t)(i0 + sr) * TWON + k;
            short8 aE0 = *reinterpret_cast<const short8*>(ep);
            short8 aE1 = *reinterpret_cast<const short8*>(ep + 8);
            float4 p0 = *reinterpret_cast<const float4*>(Pj + k);
            float4 p1 = *reinterpret_cast<const float4*>(Pj + k + 4);
            float4 p2 = *reinterpret_cast<const float4*>(Pj + k + 8);
            float4 p3 = *reinterpret_cast<const float4*>(Pj + k + 12);
            const float arg = Ct[iblk * 64 + ((kbase + it * 64) >> 7)] - rmh;
            short8 g0, g1;
            g0[0] = (short)f2bf(bf2f((u16)aE0[0]) * __expf(arg + p0.x));
            g0[1] = (short)f2bf(bf2f((u16)aE0[1]) * __expf(arg + p0.y));
            g0[2] = (short)f2bf(bf2f((u16)aE0[2]) * __expf(arg + p0.z));
            g0[3] = (short)f2bf(bf2f((u16)aE0[3]) * __expf(arg + p0.w));
            g0[4] = (short)f2bf(bf2f((u16)aE0[4]) * __expf(arg + p1.x));
            g0[5] = (short)f2bf(bf2f((u16)aE0[5]) * __expf(arg + p1.y));
            g0[6] = (short)f2bf(bf2f((u16)aE0[6]) * __expf(arg + p1.z));
            g0[7] = (short)f2bf(bf2f((u16)aE0[7]) * __expf(arg + p1.w));
            g1[0] = (short)f2bf(bf2f((u16)aE1[0]) * __expf(arg + p2.x));
            g1[1] = (short)f2bf(bf2f((u16)aE1[1]) * __expf(arg + p2.y));
            g1[2] = (short)f2bf(bf2f((u16)aE1[2]) * __expf(arg + p2.z));
            g1[3] = (short)f2bf(bf2f((u16)aE1[3]) * __expf(arg + p2.w));
            g1[4] = (short)f2bf(bf2f((u16)aE1[4]) * __expf(arg + p3.x));
            g1[5] = (short)f2bf(bf2f((u16)aE1[5]) * __expf(arg + p3.y));
            g1[6] = (short)f2bf(bf2f((u16)aE1[6]) * __expf(arg + p3.z));
            g1[7] = (short)f2bf(bf2f((u16)aE1[7]) * __expf(arg + p3.w));
            *reinterpret_cast<short8*>(lds + aw0) = g0;
            *reinterpret_cast<short8*>(lds + aw1) = g1;
        }
        asm volatile("s_waitcnt vmcnt(0)" ::: "memory");
        __builtin_amdgcn_sched_barrier(0);
        __syncthreads();
        // ---- MFMA: A and B both from LDS
        #pragma unroll
        for (int kk = 0; kk < 2; ++kk) {
            short8 af[4], bfr[2];
            #pragma unroll
            for (int m = 0; m < 4; ++m) {
                const int row = mh * 64 + m * 16 + (lane & 15);
                const int off = row * 128 +
                                ((kk * 64 + (lane >> 4) * 16) ^ ((row & 7) << 4));
                af[m] = *reinterpret_cast<const short8*>(lds + off);
            }
            #pragma unroll
            for (int n = 0; n < 2; ++n) {
                const int row = dq * 32 + n * 16 + (lane & 15);
                const int off = 16384 + row * 128 +
                                ((kk * 64 + (lane >> 4) * 16) ^ ((row & 7) << 4));
                bfr[n] = *reinterpret_cast<const short8*>(lds + off);
            }
            #pragma unroll
            for (int m = 0; m < 4; ++m)
                #pragma unroll
                for (int n = 0; n < 2; ++n)
                    acc[m][n] = mfma16b(af[m], bfr[n], acc[m][n]);
        }
    }
    // ---- epilogue: pack acc*rrs to bf16 pairs, raw lane-order coalesced store
    unsigned* pout = part + ((size_t)(kslice * 128 + idx2) * 512 + t) * 16;
    #pragma unroll
    for (int m = 0; m < 4; ++m) {
        float rf[4];
        #pragma unroll
        for (int r4 = 0; r4 < 4; ++r4)
            rf[r4] = rrs[i0 + mh * 64 + m * 16 + (lane >> 4) * 4 + r4];
        unsigned pk[4];
        #pragma unroll
        for (int n = 0; n < 2; ++n) {
            pk[n * 2]     = (unsigned)f2bf(acc[m][n][0] * rf[0]) |
                            ((unsigned)f2bf(acc[m][n][1] * rf[1]) << 16);
            pk[n * 2 + 1] = (unsigned)f2bf(acc[m][n][2] * rf[2]) |
                            ((unsigned)f2bf(acc[m][n][3] * rf[3]) << 16);
        }
        *reinterpret_cast<uint4*>(pout + m * 4) = *reinterpret_cast<uint4*>(pk);
    }
}

// ---------------- reduce: sum 8 packed-bf16 raw-order slices -> out[i][d] f32
__global__ __launch_bounds__(512)
void reduce_k(const unsigned* __restrict__ part, float* __restrict__ out) {
    const int b = blockIdx.x;            // 0..511: mq | pos(=iblk*4+db)
    const int mq = b & 3, pos = b >> 2;
    const int db = pos & 3, iblk = pos >> 2;
    const int t = threadIdx.x;
    const int lane = t & 63, wave = t >> 6;
    const int mh = wave >> 2, dq = wave & 3;
    float s[8] = {};
    #pragma unroll
    for (int ks = 0; ks < 8; ++ks) {
        const unsigned* p = part + ((size_t)(ks * 128 + pos) * 512 + t) * 16 + mq * 4;
        uint4 a = *reinterpret_cast<const uint4*>(p);
        unsigned u[4] = {a.x, a.y, a.z, a.w};
        #pragma unroll
        for (int n = 0; n < 2; ++n) {
            s[n * 4 + 0] += bf2f((u16)(u[n * 2] & 0xffffu));
            s[n * 4 + 1] += bf2f((u16)(u[n * 2] >> 16));
            s[n * 4 + 2] += bf2f((u16)(u[n * 2 + 1] & 0xffffu));
            s[n * 4 + 3] += bf2f((u16)(u[n * 2 + 1] >> 16));
        }
    }
    #pragma unroll
    for (int n = 0; n < 2; ++n)
        #pragma unroll
        for (int r4 = 0; r4 < 4; ++r4) {
            const int i = iblk * 128 + mh * 64 + mq * 16 + (lane >> 4) * 4 + r4;
            const int d = db * 128 + dq * 32 + n * 16 + (lane & 15);
            out[(size_t)i * DD + d] = s[n * 4 + r4];
        }
}

extern "C" void kernel_launch(void* const* d_in, const int* in_sizes, int n_in,
                              void* d_out, int out_size, void* d_ws, size_t ws_size,
                              hipStream_t stream) {
    const float* x = (const float*)d_in[0];
    const float* y = (const float*)d_in[1];
    float* out = (float*)d_out;

    char* w = (char*)d_ws;
    const size_t OFF_EF   = 0;                          // Ef bf16: 64 MiB
    const size_t OFF_BHI  = 67108864;                   // bhi f16: 8 MiB
    const size_t OFF_B2T  = OFF_BHI + 8388608;          // b2t bf16: 8 MiB
    const size_t OFF_PART = OFF_B2T + 8388608;          // part packed bf16: 32 MiB
    const size_t OFF_RPM  = OFF_PART + 67108864;        // 1 MiB each
    const size_t OFF_RPS  = OFF_RPM + 1048576;
    const size_t OFF_CPM  = OFF_RPS + 1048576;
    const size_t OFF_CPS  = OFF_CPM + 1048576;
    const size_t OFF_CT   = OFF_CPS + 1048576;          // 8 KiB (+pad)
    const size_t OFF_TAIL = OFF_CT + 65536;

    u16*      Ef   = (u16*)(w + OFF_EF);
    half_t*   bhi  = (half_t*)(w + OFF_BHI);
    u16*      b2t  = (u16*)(w + OFF_B2T);
    unsigned* part = (unsigned*)(w + OFF_PART);
    float*    rpm  = (float*)(w + OFF_RPM);
    float*    rps  = (float*)(w + OFF_RPS);
    float*    cpm  = (float*)(w + OFF_CPM);
    float*    cps  = (float*)(w + OFF_CPS);
    float*    Ct   = (float*)(w + OFF_CT);
    float*    nb   = (float*)(w + OFF_TAIL);            // 8192
    float*    rm   = nb  + TWON;                        // 4096
    float*    rrs  = rm  + NN;                          // 4096
    float*    Pj   = rrs + NN;                          // 8192

    prep_k<<<TWON, 64, 0, stream>>>(x, y, bhi, nb);
    gemm1_k<<<dim3(TWON / 128, NN / 128), 256, 0, stream>>>(bhi, nb, Ef, Ct,
                                                            rpm, rps, cpm, cps);
    row_comb_k<<<NN / 256, 256, 0, stream>>>(rpm, rps, rm, rrs);
    col_comb_k<<<TWON / 256, 256, 0, stream>>>(cpm, cps, Pj);
    b2tr_k<<<dim3(TWON / 32, DD / 32), dim3(32, 8), 0, stream>>>(bhi, b2t);
    gemm2_k<<<1024, 512, 0, stream>>>(Ef, b2t, Ct, rm, Pj, rrs, part);
    reduce_k<<<512, 512, 0, stream>>>(part, out);
}

// Round 19
// 175.476 us; speedup vs baseline: 1.2096x; 1.0681x over previous
//
#include <hip/hip_runtime.h>
#include <math.h>

#define NN   4096
#define DD   512
#define TWON 8192

typedef _Float16 half_t;
typedef unsigned short u16;
using half8  = __attribute__((ext_vector_type(8))) half_t;
using short8 = __attribute__((ext_vector_type(8))) short;
using f32x4  = __attribute__((ext_vector_type(4))) float;

#define NLOG2E_10 (-14.4269504089f)   // -10 * log2(e)

__device__ __forceinline__ float exp2_f(float x) { return __builtin_amdgcn_exp2f(x); }
__device__ __forceinline__ float log2_f(float x) { return __builtin_amdgcn_logf(x); }
__device__ __forceinline__ float sqrt_f(float x) { return __builtin_amdgcn_sqrtf(x); }

__device__ __forceinline__ u16 f2bf(float f) {
    unsigned u = __float_as_uint(f);
    u += 0x7fffu + ((u >> 16) & 1u);
    return (u16)(u >> 16);
}
__device__ __forceinline__ float bf2f(u16 h) {
    return __uint_as_float(((unsigned)h) << 16);
}
__device__ __forceinline__ void gl16(const void* g, void* l) {
    __builtin_amdgcn_global_load_lds(
        (const __attribute__((address_space(1))) void*)g,
        (__attribute__((address_space(3))) void*)l, 16, 0, 0);
}
__device__ __forceinline__ f32x4 mfma16h(half8 a, half8 b, f32x4 c) {
    return __builtin_amdgcn_mfma_f32_16x16x32_f16(a, b, c, 0, 0, 0);
}
__device__ __forceinline__ f32x4 mfma16b(short8 a, short8 b, f32x4 c) {
    return __builtin_amdgcn_mfma_f32_16x16x32_bf16(a, b, c, 0, 0, 0);
}

// ---------------- prep: b=[y;x] -> f16 + norms nb[8192]
__global__ __launch_bounds__(64)
void prep_k(const float* __restrict__ x, const float* __restrict__ y,
            half_t* __restrict__ bhi, float* __restrict__ nb) {
    int r = blockIdx.x;           // 0..8191
    int l = threadIdx.x;          // 64
    const float* src = (r < NN) ? (y + (size_t)r * DD) : (x + (size_t)(r - NN) * DD);
    float4 v0 = *reinterpret_cast<const float4*>(src + l * 8);
    float4 v1 = *reinterpret_cast<const float4*>(src + l * 8 + 4);
    float e[8] = {v0.x, v0.y, v0.z, v0.w, v1.x, v1.y, v1.z, v1.w};
    float s = 0.f;
    half8 h;
    #pragma unroll
    for (int q = 0; q < 8; ++q) {
        s += e[q] * e[q];
        h[q] = (half_t)e[q];
    }
    *reinterpret_cast<half8*>(bhi + (size_t)r * DD + l * 8) = h;
    #pragma unroll
    for (int off = 32; off; off >>= 1) s += __shfl_down(s, off);
    if (l == 0) nb[r] = s;
}

// ---------------- b2tr: b2t[d][k] = sign(k) * bhi[k][d] (bf16). Separate bufs.
__global__ __launch_bounds__(256)
void b2tr_k(const half_t* __restrict__ bhi, u16* __restrict__ b2t) {
    __shared__ half_t tl[32][33];
    int k0 = blockIdx.x * 32, d0 = blockIdx.y * 32;
    int tx = threadIdx.x, ty = threadIdx.y;   // (32,8)
    #pragma unroll
    for (int j = 0; j < 4; ++j)
        tl[ty + 8 * j][tx] = bhi[(size_t)(k0 + ty + 8 * j) * DD + d0 + tx];
    __syncthreads();
    float sgn = (k0 < NN) ? 1.f : -1.f;
    #pragma unroll
    for (int j = 0; j < 4; ++j) {
        float v = (float)tl[tx][ty + 8 * j] * sgn;
        b2t[(size_t)(d0 + ty + 8 * j) * TWON + k0 + tx] = f2bf(v);
    }
}

// ---------------- GEMM1: f16 MFMA, swapped operands (rows=j, cols=i), logits in
// log2 domain, shared-C2 epilogue. Stores E=exp2(l2-C2) bf16 (trunc-pack, 8B
// stores), Ct=C2 per tile, rpm/rps row partials, cpm/cps col partials.
__global__ __launch_bounds__(256)
void gemm1_k(const half_t* __restrict__ bhi,
             const float* __restrict__ nb, u16* __restrict__ Ef,
             float* __restrict__ Ct,
             float* __restrict__ rpm, float* __restrict__ rps,
             float* __restrict__ cpm, float* __restrict__ cps) {
    __shared__ unsigned char lds[32768]; // Ahi@0 Bhi@16K, each 128x64 f16 swizzled
    const int t = threadIdx.x;
    const int wave = t >> 6, lane = t & 63;
    const int i0 = blockIdx.y * 128, j0 = blockIdx.x * 128;
    const int wm = (wave >> 1) * 64, wn = (wave & 1) * 64;
    const half_t* ahig = bhi + (size_t)NN * DD;  // x rows are b rows 4096..8191
    f32x4 acc[4][4] = {};
    for (int k0 = 0; k0 < DD; k0 += 64) {
        __syncthreads();
        #pragma unroll
        for (int q = 0; q < 4; ++q) {
            const int dbase = (wave * 4 + q) * 1024;
            const int p  = dbase + lane * 16;
            const int r  = p >> 7;
            const int cb = (p & 127) ^ ((r & 7) << 4);
            const size_t offA = (size_t)(i0 + r) * DD + k0 + (cb >> 1);
            const size_t offB = (size_t)(j0 + r) * DD + k0 + (cb >> 1);
            gl16(ahig + offA, lds + dbase);
            gl16(bhi  + offB, lds + 16384 + dbase);
        }
        asm volatile("s_waitcnt vmcnt(0)" ::: "memory");
        __builtin_amdgcn_sched_barrier(0);
        __syncthreads();
        #pragma unroll
        for (int kk = 0; kk < 2; ++kk) {
            half8 ah[4];
            #pragma unroll
            for (int m = 0; m < 4; ++m) {
                const int row = wm + m * 16 + (lane & 15);
                const int off = row * 128 + ((kk * 64 + (lane >> 4) * 16) ^ ((row & 7) << 4));
                ah[m] = *reinterpret_cast<const half8*>(lds + off);
            }
            #pragma unroll
            for (int n = 0; n < 4; ++n) {
                const int row = wn + n * 16 + (lane & 15);
                const int off = row * 128 + ((kk * 64 + (lane >> 4) * 16) ^ ((row & 7) << 4));
                half8 bh = *reinterpret_cast<const half8*>(lds + 16384 + off);
                #pragma unroll
                for (int m = 0; m < 4; ++m)
                    acc[m][n] = mfma16h(bh, ah[m], acc[m][n]);   // rows=j, cols=i
            }
        }
    }
    // acc[m][n][reg]: j = j0+wn+n*16+(lane>>4)*4+reg ; i = i0+wm+m*16+(lane&15)
    // ---- pass 1: acc -> log2-logits, track thread max
    float nxi[4];
    #pragma unroll
    for (int m = 0; m < 4; ++m) nxi[m] = nb[NN + i0 + wm + m * 16 + (lane & 15)];
    float4 nbj4[4];
    #pragma unroll
    for (int n = 0; n < 4; ++n)
        nbj4[n] = *reinterpret_cast<const float4*>(nb + j0 + wn + n * 16 + (lane >> 4) * 4);
    float tmax = -3.0e38f;
    #pragma unroll
    for (int m = 0; m < 4; ++m) {
        const int irel = i0 + wm + m * 16 + (lane & 15) + NN - j0;  // diag: jrel == irel
        #pragma unroll
        for (int n = 0; n < 4; ++n) {
            #pragma unroll
            for (int r4 = 0; r4 < 4; ++r4) {
                const int jrel = wn + n * 16 + (lane >> 4) * 4 + r4;
                float nbj = (r4 == 0) ? nbj4[n].x : (r4 == 1) ? nbj4[n].y
                          : (r4 == 2) ? nbj4[n].z : nbj4[n].w;
                float sq = nxi[m] + nbj - 2.0f * acc[m][n][r4];
                float lg = NLOG2E_10 * sqrt_f(fmaxf(sq, 1e-12f));
                if (jrel == irel) lg = -1e7f;
                acc[m][n][r4] = lg;
                tmax = fmaxf(tmax, lg);
            }
        }
    }
    // ---- block-wide shared max C2
    #pragma unroll
    for (int off = 1; off < 64; off <<= 1) tmax = fmaxf(tmax, __shfl_xor(tmax, off));
    __syncthreads();
    float* red = reinterpret_cast<float*>(lds);
    if (lane == 0) red[wave] = tmax;
    __syncthreads();
    const float C = fmaxf(fmaxf(red[0], red[1]), fmaxf(red[2], red[3]));
    __syncthreads();
    if (t == 0) Ct[blockIdx.y * 64 + blockIdx.x] = C;
    // ---- pass 2: single exp2; trunc-pack bf16 E (8B stores); row/col partials
    float rs[4] = {}, cs[16] = {};
    #pragma unroll
    for (int m = 0; m < 4; ++m) {
        const size_t ibase = (size_t)(i0 + wm + m * 16 + (lane & 15)) * TWON;
        #pragma unroll
        for (int n = 0; n < 4; ++n) {
            float e0 = exp2_f(acc[m][n][0] - C);
            float e1 = exp2_f(acc[m][n][1] - C);
            float e2 = exp2_f(acc[m][n][2] - C);
            float e3 = exp2_f(acc[m][n][3] - C);
            uint2 pk;
            pk.x = (__float_as_uint(e0) >> 16) | (__float_as_uint(e1) & 0xffff0000u);
            pk.y = (__float_as_uint(e2) >> 16) | (__float_as_uint(e3) & 0xffff0000u);
            const int j = j0 + wn + n * 16 + (lane >> 4) * 4;
            *reinterpret_cast<uint2*>(Ef + ibase + j) = pk;
            rs[m] += e0 + e1 + e2 + e3;
            cs[n * 4 + 0] += e0; cs[n * 4 + 1] += e1;
            cs[n * 4 + 2] += e2; cs[n * 4 + 3] += e3;
        }
    }
    // rows: reduce over lane>>4 (same i across quads)
    #pragma unroll
    for (int off = 16; off < 64; off <<= 1) {
        #pragma unroll
        for (int m = 0; m < 4; ++m) rs[m] += __shfl_xor(rs[m], off);
    }
    // cols: reduce over lane&15 (same j across i-cols)
    #pragma unroll
    for (int off = 1; off < 16; off <<= 1) {
        #pragma unroll
        for (int q = 0; q < 16; ++q) cs[q] += __shfl_xor(cs[q], off);
    }
    // ---- cross-wave combine: rows red[0..255], cols red[256..511]
    if (lane < 16) {
        #pragma unroll
        for (int m = 0; m < 4; ++m)
            red[(wave & 1) * 128 + wm + m * 16 + lane] = rs[m];
    }
    if ((lane & 15) == 0) {
        #pragma unroll
        for (int n = 0; n < 4; ++n)
            #pragma unroll
            for (int r4 = 0; r4 < 4; ++r4)
                red[256 + (wave >> 1) * 128 + (wave & 1) * 64 + n * 16 + (lane >> 4) * 4 + r4]
                    = cs[n * 4 + r4];
    }
    __syncthreads();
    if (t < 128) {
        float S = red[t] + red[128 + t];
        rpm[(size_t)blockIdx.x * NN + i0 + t] = C;
        rps[(size_t)blockIdx.x * NN + i0 + t] = S;
    } else {
        const int c = t - 128;
        float S = red[256 + c] + red[384 + c];
        cpm[(size_t)blockIdx.y * TWON + j0 + c] = C;
        cps[(size_t)blockIdx.y * TWON + j0 + c] = S;
    }
}

// ---------------- fused combines (log2 domain): blocks 0..15 rows -> rm,rrs;
// blocks 16..47 cols -> Pj = -cm2/2 - log2(Sc)/2
__global__ __launch_bounds__(256)
void comb_k(const float* __restrict__ rpm, const float* __restrict__ rps,
            const float* __restrict__ cpm, const float* __restrict__ cps,
            float* __restrict__ rm, float* __restrict__ rrs, float* __restrict__ Pj) {
    const int b = blockIdx.x;
    if (b < 16) {
        int i = b * 256 + threadIdx.x;
        float M = -3.0e38f;
        for (int tt = 0; tt < TWON / 128; ++tt) M = fmaxf(M, rpm[(size_t)tt * NN + i]);
        float S = 0.f;
        for (int tt = 0; tt < TWON / 128; ++tt)
            S += rps[(size_t)tt * NN + i] * exp2_f(rpm[(size_t)tt * NN + i] - M);
        rm[i] = M; rrs[i] = rsqrtf(S);
    } else {
        int j = (b - 16) * 256 + threadIdx.x;
        float M = -3.0e38f;
        for (int tt = 0; tt < NN / 128; ++tt) M = fmaxf(M, cpm[(size_t)tt * TWON + j]);
        float S = 0.f;
        for (int tt = 0; tt < NN / 128; ++tt)
            S += cps[(size_t)tt * TWON + j] * exp2_f(cpm[(size_t)tt * TWON + j] - M);
        Pj[j] = -0.5f * M - 0.5f * log2_f(S);
    }
}

// ---------------- GEMM2 v4 (r16-proven): block 128i x 128d x 1024k; grid 1024.
// Both operands LDS-staged; single-buffer phase; exp2 + trunc-pack in STOREA.
__global__ __launch_bounds__(512, 4)
void gemm2_k(const u16* __restrict__ Ef, const u16* __restrict__ b2t,
             const float* __restrict__ Ct, const float* __restrict__ rm,
             const float* __restrict__ Pj, const float* __restrict__ rrs,
             unsigned* __restrict__ part) {
    __shared__ unsigned char lds[32768];   // A 128x64 bf16 @0, B 128x64 bf16 @16384
    const int t = threadIdx.x;
    const int wave = t >> 6, lane = t & 63;
    const int sw = blockIdx.x;             // 0..1023
    const int kslice = sw & 7;             // = XCD (round-robin dispatch)
    const int idx2 = sw >> 3;              // 0..127
    const int db = idx2 & 3;               // d-block
    const int iblk = idx2 >> 2;            // 0..31
    const int i0 = iblk * 128;
    const int d0 = db * 128;
    const int kbase = kslice * 1024;
    const int mh = wave >> 2, dq = wave & 3;
    const int sr = t >> 2;                 // A staging row 0..127
    const int kc = (t & 3) * 16;           // A staging k-offset (elements)
    const int aw0 = sr * 128 + ((kc * 2) ^ ((sr & 7) << 4));
    const int aw1 = sr * 128 + (((kc + 8) * 2) ^ ((sr & 7) << 4));
    const float rmh = 0.5f * rm[i0 + sr];
    const int NT = 16;                     // 1024 / 64
    f32x4 acc[4][2] = {};
    for (int it = 0; it < NT; ++it) {
        __syncthreads();
        // ---- B stage via gl16 (pre-swizzled source, linear LDS dest)
        #pragma unroll
        for (int q = 0; q < 2; ++q) {
            const int dbase = (wave * 2 + q) * 1024;
            const int p  = dbase + lane * 16;
            const int r  = p >> 7;                      // d-row 0..127
            const int cb = (p & 127) ^ ((r & 7) << 4);
            gl16(b2t + (size_t)(d0 + r) * TWON + kbase + it * 64 + (cb >> 1),
                 lds + 16384 + dbase);
        }
        // ---- A stage: Ef row + fused exp2 -> swizzled ds_write (trunc pack)
        {
            const int k = kbase + it * 64 + kc;
            const u16* ep = Ef + (size_t)(i0 + sr) * TWON + k;
            short8 aE0 = *reinterpret_cast<const short8*>(ep);
            short8 aE1 = *reinterpret_cast<const short8*>(ep + 8);
            float4 p0 = *reinterpret_cast<const float4*>(Pj + k);
            float4 p1 = *reinterpret_cast<const float4*>(Pj + k + 4);
            float4 p2 = *reinterpret_cast<const float4*>(Pj + k + 8);
            float4 p3 = *reinterpret_cast<const float4*>(Pj + k + 12);
            const float arg = Ct[iblk * 64 + ((kbase + it * 64) >> 7)] - rmh;
            short8 g0, g1;
            g0[0] = (short)(__float_as_uint(bf2f((u16)aE0[0]) * exp2_f(arg + p0.x)) >> 16);
            g0[1] = (short)(__float_as_uint(bf2f((u16)aE0[1]) * exp2_f(arg + p0.y)) >> 16);
            g0[2] = (short)(__float_as_uint(bf2f((u16)aE0[2]) * exp2_f(arg + p0.z)) >> 16);
            g0[3] = (short)(__float_as_uint(bf2f((u16)aE0[3]) * exp2_f(arg + p0.w)) >> 16);
            g0[4] = (short)(__float_as_uint(bf2f((u16)aE0[4]) * exp2_f(arg + p1.x)) >> 16);
            g0[5] = (short)(__float_as_uint(bf2f((u16)aE0[5]) * exp2_f(arg + p1.y)) >> 16);
            g0[6] = (short)(__float_as_uint(bf2f((u16)aE0[6]) * exp2_f(arg + p1.z)) >> 16);
            g0[7] = (short)(__float_as_uint(bf2f((u16)aE0[7]) * exp2_f(arg + p1.w)) >> 16);
            g1[0] = (short)(__float_as_uint(bf2f((u16)aE1[0]) * exp2_f(arg + p2.x)) >> 16);
            g1[1] = (short)(__float_as_uint(bf2f((u16)aE1[1]) * exp2_f(arg + p2.y)) >> 16);
            g1[2] = (short)(__float_as_uint(bf2f((u16)aE1[2]) * exp2_f(arg + p2.z)) >> 16);
            g1[3] = (short)(__float_as_uint(bf2f((u16)aE1[3]) * exp2_f(arg + p2.w)) >> 16);
            g1[4] = (short)(__float_as_uint(bf2f((u16)aE1[4]) * exp2_f(arg + p3.x)) >> 16);
            g1[5] = (short)(__float_as_uint(bf2f((u16)aE1[5]) * exp2_f(arg + p3.y)) >> 16);
            g1[6] = (short)(__float_as_uint(bf2f((u16)aE1[6]) * exp2_f(arg + p3.z)) >> 16);
            g1[7] = (short)(__float_as_uint(bf2f((u16)aE1[7]) * exp2_f(arg + p3.w)) >> 16);
            *reinterpret_cast<short8*>(lds + aw0) = g0;
            *reinterpret_cast<short8*>(lds + aw1) = g1;
        }
        asm volatile("s_waitcnt vmcnt(0)" ::: "memory");
        __builtin_amdgcn_sched_barrier(0);
        __syncthreads();
        // ---- MFMA: A and B both from LDS
        #pragma unroll
        for (int kk = 0; kk < 2; ++kk) {
            short8 af[4], bfr[2];
            #pragma unroll
            for (int m = 0; m < 4; ++m) {
                const int row = mh * 64 + m * 16 + (lane & 15);
                const int off = row * 128 +
                                ((kk * 64 + (lane >> 4) * 16) ^ ((row & 7) << 4));
                af[m] = *reinterpret_cast<const short8*>(lds + off);
            }
            #pragma unroll
            for (int n = 0; n < 2; ++n) {
                const int row = dq * 32 + n * 16 + (lane & 15);
                const int off = 16384 + row * 128 +
                                ((kk * 64 + (lane >> 4) * 16) ^ ((row & 7) << 4));
                bfr[n] = *reinterpret_cast<const short8*>(lds + off);
            }
            #pragma unroll
            for (int m = 0; m < 4; ++m)
                #pragma unroll
                for (int n = 0; n < 2; ++n)
                    acc[m][n] = mfma16b(af[m], bfr[n], acc[m][n]);
        }
    }
    // ---- epilogue: pack acc*rrs to bf16 pairs, raw lane-order coalesced store
    unsigned* pout = part + ((size_t)(kslice * 128 + idx2) * 512 + t) * 16;
    #pragma unroll
    for (int m = 0; m < 4; ++m) {
        float rf[4];
        #pragma unroll
        for (int r4 = 0; r4 < 4; ++r4)
            rf[r4] = rrs[i0 + mh * 64 + m * 16 + (lane >> 4) * 4 + r4];
        unsigned pk[4];
        #pragma unroll
        for (int n = 0; n < 2; ++n) {
            pk[n * 2]     = (unsigned)f2bf(acc[m][n][0] * rf[0]) |
                            ((unsigned)f2bf(acc[m][n][1] * rf[1]) << 16);
            pk[n * 2 + 1] = (unsigned)f2bf(acc[m][n][2] * rf[2]) |
                            ((unsigned)f2bf(acc[m][n][3] * rf[3]) << 16);
        }
        *reinterpret_cast<uint4*>(pout + m * 4) = *reinterpret_cast<uint4*>(pk);
    }
}

// ---------------- reduce: sum 8 packed-bf16 raw-order slices -> out[i][d] f32
__global__ __launch_bounds__(512)
void reduce_k(const unsigned* __restrict__ part, float* __restrict__ out) {
    const int b = blockIdx.x;            // 0..511: mq | pos(=iblk*4+db)
    const int mq = b & 3, pos = b >> 2;
    const int db = pos & 3, iblk = pos >> 2;
    const int t = threadIdx.x;
    const int lane = t & 63, wave = t >> 6;
    const int mh = wave >> 2, dq = wave & 3;
    float s[8] = {};
    #pragma unroll
    for (int ks = 0; ks < 8; ++ks) {
        const unsigned* p = part + ((size_t)(ks * 128 + pos) * 512 + t) * 16 + mq * 4;
        uint4 a = *reinterpret_cast<const uint4*>(p);
        unsigned u[4] = {a.x, a.y, a.z, a.w};
        #pragma unroll
        for (int n = 0; n < 2; ++n) {
            s[n * 4 + 0] += bf2f((u16)(u[n * 2] & 0xffffu));
            s[n * 4 + 1] += bf2f((u16)(u[n * 2] >> 16));
            s[n * 4 + 2] += bf2f((u16)(u[n * 2 + 1] & 0xffffu));
            s[n * 4 + 3] += bf2f((u16)(u[n * 2 + 1] >> 16));
        }
    }
    #pragma unroll
    for (int n = 0; n < 2; ++n)
        #pragma unroll
        for (int r4 = 0; r4 < 4; ++r4) {
            const int i = iblk * 128 + mh * 64 + mq * 16 + (lane >> 4) * 4 + r4;
            const int d = db * 128 + dq * 32 + n * 16 + (lane & 15);
            out[(size_t)i * DD + d] = s[n * 4 + r4];
        }
}

extern "C" void kernel_launch(void* const* d_in, const int* in_sizes, int n_in,
                              void* d_out, int out_size, void* d_ws, size_t ws_size,
                              hipStream_t stream) {
    const float* x = (const float*)d_in[0];
    const float* y = (const float*)d_in[1];
    float* out = (float*)d_out;

    char* w = (char*)d_ws;
    const size_t OFF_EF   = 0;                          // Ef bf16: 64 MiB
    const size_t OFF_BHI  = 67108864;                   // bhi f16: 8 MiB
    const size_t OFF_B2T  = OFF_BHI + 8388608;          // b2t bf16: 8 MiB
    const size_t OFF_PART = OFF_B2T + 8388608;          // part packed bf16: 32 MiB
    const size_t OFF_RPM  = OFF_PART + 67108864;        // 1 MiB each
    const size_t OFF_RPS  = OFF_RPM + 1048576;
    const size_t OFF_CPM  = OFF_RPS + 1048576;
    const size_t OFF_CPS  = OFF_CPM + 1048576;
    const size_t OFF_CT   = OFF_CPS + 1048576;          // 8 KiB (+pad)
    const size_t OFF_TAIL = OFF_CT + 65536;

    u16*      Ef   = (u16*)(w + OFF_EF);
    half_t*   bhi  = (half_t*)(w + OFF_BHI);
    u16*      b2t  = (u16*)(w + OFF_B2T);
    unsigned* part = (unsigned*)(w + OFF_PART);
    float*    rpm  = (float*)(w + OFF_RPM);
    float*    rps  = (float*)(w + OFF_RPS);
    float*    cpm  = (float*)(w + OFF_CPM);
    float*    cps  = (float*)(w + OFF_CPS);
    float*    Ct   = (float*)(w + OFF_CT);
    float*    nb   = (float*)(w + OFF_TAIL);            // 8192
    float*    rm   = nb  + TWON;                        // 4096
    float*    rrs  = rm  + NN;                          // 4096
    float*    Pj   = rrs + NN;                          // 8192

    prep_k<<<TWON, 64, 0, stream>>>(x, y, bhi, nb);
    gemm1_k<<<dim3(TWON / 128, NN / 128), 256, 0, stream>>>(bhi, nb, Ef, Ct,
                                                            rpm, rps, cpm, cps);
    comb_k<<<48, 256, 0, stream>>>(rpm, rps, cpm, cps, rm, rrs, Pj);
    b2tr_k<<<dim3(TWON / 32, DD / 32), dim3(32, 8), 0, stream>>>(bhi, b2t);
    gemm2_k<<<1024, 512, 0, stream>>>(Ef, b2t, Ct, rm, Pj, rrs, part);
    reduce_k<<<512, 512, 0, stream>>>(part, out);
}